// Round 9
// baseline (127.409 us; speedup 1.0000x reference)
//
#include <hip/hip_runtime.h>
#include <hip/hip_bf16.h>
#include <cstdint>

// Problem dims (fixed by reference setup_inputs)
constexpr int Bn = 16;    // batch
constexpr int Sn = 1024;  // source length
constexpr int Tn = 512;   // query steps
constexpr int QD = 256;   // query vec size
constexpr int En = 512;   // src encoding size
constexpr int Hn = 4;     // heads
constexpr float SLOPE = 0.01f;   // jax.nn.leaky_relu default
constexpr float NEG_INF = -1e9f;
constexpr int Mn = Bn * Sn;      // 16384 rows of the projection GEMM

typedef _Float16 f16;
typedef f16 f16x4 __attribute__((ext_vector_type(4)));
typedef f16 f16x8 __attribute__((ext_vector_type(8)));
typedef float f32x4 __attribute__((ext_vector_type(4)));

// async global->LDS, 16B per lane; dest = wave-uniform base + lane*16
#define G2L(g, l) __builtin_amdgcn_global_load_lds(                      \
    (const __attribute__((address_space(1))) void*)(g),                  \
    (__attribute__((address_space(3))) void*)(l), 16, 0, 0)

#define VM12 asm volatile("s_waitcnt vmcnt(12)" ::: "memory")
#define VM8  asm volatile("s_waitcnt vmcnt(8)"  ::: "memory")
#define VM4  asm volatile("s_waitcnt vmcnt(4)"  ::: "memory")
#define VM0  asm volatile("s_waitcnt vmcnt(0)"  ::: "memory")

// ---------------------------------------------------------------------------
// K0: detect mask dtype (bool bytes vs int32) — writes flag (1 = int32) to ws
// ---------------------------------------------------------------------------
__global__ void detect_mask_kernel(const unsigned char* __restrict__ mask_bytes,
                                   int* __restrict__ flag) {
    __shared__ int cnt;
    if (threadIdx.x == 0) cnt = 0;
    __syncthreads();
    int local = 0;
    for (int p = threadIdx.x; p < 4096; p += 256) {
        if ((p & 3) != 0 && mask_bytes[p] != 0) local++;
    }
    atomicAdd(&cnt, local);
    __syncthreads();
    if (threadIdx.x == 0) flag[0] = (cnt == 0) ? 1 : 0;
}

// ---------------------------------------------------------------------------
// C1: split src (16384x512 f32) into Ah + Al (f16 row-major), exact hi/lo
// ---------------------------------------------------------------------------
__global__ __launch_bounds__(256) void conv_a_kernel(
    const float* __restrict__ src, f16* __restrict__ Ah, f16* __restrict__ Al)
{
    const size_t i4 = (size_t)blockIdx.x * 256 + threadIdx.x;
    const size_t base = i4 * 4;
    const float4 v = *(const float4*)(src + base);
    f16x4 hi, lo;
    const float xs[4] = {v.x, v.y, v.z, v.w};
    #pragma unroll
    for (int j = 0; j < 4; ++j) {
        f16 h = (f16)xs[j];
        hi[j] = h;
        lo[j] = (f16)(xs[j] - (float)h);
    }
    *(f16x4*)(Ah + base) = hi;
    *(f16x4*)(Al + base) = lo;
}

// ---------------------------------------------------------------------------
// C2: W (512x1024 f32) -> Bht, Blt (1024x512 f16) transposed + hi/lo split
// ---------------------------------------------------------------------------
__global__ __launch_bounds__(256) void conv_b_kernel(
    const float* __restrict__ W, f16* __restrict__ Bht, f16* __restrict__ Blt)
{
    __shared__ float T[64][65];
    const int tid = threadIdx.x;
    const int n0 = blockIdx.x * 64;
    const int k0 = blockIdx.y * 64;
    #pragma unroll
    for (int p = 0; p < 4; ++p) {
        const int e = p * 256 + tid;
        const int r = e >> 4;
        const int c4 = e & 15;
        const float4 v = *(const float4*)(W + (size_t)(k0 + r) * (Hn * QD) + n0 + c4 * 4);
        T[r][c4 * 4 + 0] = v.x; T[r][c4 * 4 + 1] = v.y;
        T[r][c4 * 4 + 2] = v.z; T[r][c4 * 4 + 3] = v.w;
    }
    __syncthreads();
    #pragma unroll
    for (int p = 0; p < 4; ++p) {
        const int e = p * 256 + tid;
        const int r = e >> 4;
        const int c4 = e & 15;
        f16x4 hi, lo;
        #pragma unroll
        for (int j = 0; j < 4; ++j) {
            const float x = T[c4 * 4 + j][r];
            f16 h = (f16)x;
            hi[j] = h;
            lo[j] = (f16)(x - (float)h);
        }
        const size_t off = (size_t)(n0 + r) * En + k0 + c4 * 4;
        *(f16x4*)(Bht + off) = hi;
        *(f16x4*)(Blt + off) = lo;
    }
}

// ---------------------------------------------------------------------------
// C3: split query (512,16,256) f32 -> Qh, Ql (b,t,q) f16.
// ---------------------------------------------------------------------------
__global__ __launch_bounds__(256) void conv_q_kernel(
    const float* __restrict__ query, f16* __restrict__ Qh, f16* __restrict__ Ql)
{
    const int tid = threadIdx.x;
    const int rloc = tid >> 6;
    const int lane = tid & 63;
    const int row = blockIdx.x * 4 + rloc;   // (t,b) pair, t-major
    const int t = row >> 4, b = row & 15;
    const float4 v = *(const float4*)(query + (size_t)row * QD + lane * 4);
    f16x4 hi, lo;
    const float xs[4] = {v.x, v.y, v.z, v.w};
    #pragma unroll
    for (int j = 0; j < 4; ++j) {
        f16 h = (f16)xs[j];
        hi[j] = h;
        lo[j] = (f16)(xs[j] - (float)h);
    }
    const size_t off = ((size_t)(b * Tn + t)) * QD + lane * 4;
    *(f16x4*)(Qh + off) = hi;
    *(f16x4*)(Ql + off) = lo;
}

// ---------------------------------------------------------------------------
// K1: 128x128-tile, BK=32, RING-5 pipelined f16-split MFMA GEMM (lead-4).
//   48 K-tiles (3 split-phases x 16). 4 waves (2M x 2N), per-wave 64x64
//   (4 m-frags x 4 heads), 16 MFMA/phase. LDS 80 KB -> 2 blocks/CU.
//   Stage lead-4 (phase t stages tile t+4), 4 G2L/thread/phase.
//   Steady-state wait: vmcnt(12) (= 3 tiles in flight); tail 12->8->4->0.
//   XOR-chunk scheme (validated R6/R7): slot k4 = global k4 ^ ((row>>1)&3).
// ---------------------------------------------------------------------------
__global__ __launch_bounds__(256) void gemm1_kernel(
    const f16* __restrict__ Ah, const f16* __restrict__ Al,
    const f16* __restrict__ Bht, const f16* __restrict__ Blt,
    const float* __restrict__ wcomb,
    f16* __restrict__ Ch, f16* __restrict__ Cl)
{
    __shared__ f16 lds_f[40960];   // 5 slots x (A 4096 + B 4096) f16 = 80 KB

    const int tid = threadIdx.x;
    const int l  = tid & 63;
    const int wv = tid >> 6;         // 0..3
    const int wm = wv >> 1;          // M half (64 rows)
    const int wn = wv & 1;           // q-block (16 q)
    const int m0 = blockIdx.x * 128;
    const int q0 = blockIdx.y * 32;

    // staging constants: chunk c = tid (instr2: +256); row = c>>2, k4 = c&3
    const int rowc = tid >> 2;            // 0..63
    const int xk   = ((tid & 3) ^ ((rowc >> 1) & 3)) * 8;
    const int stgA = (m0 + rowc) * En + xk;                    // +64*En for instr2
    const int nB   = ((rowc >> 4) & 3) * QD + q0 + (rowc & 15); // +16 for instr2
    const int stgB = nB * En + xk;

    // fragment ds_read bases (f16 idx); xor nibble lane-constant
    const int xf  = ((l >> 1) & 3);
    const int aFrag = (wm * 64 + (l & 15)) * 32 + (((l >> 4) ^ xf) * 8);
    const int bFrag = 4096 + (wn * 64 + (l & 15)) * 32 + (((l >> 4) ^ xf) * 8);

    f32x4 acc[4][4];
    #pragma unroll
    for (int m = 0; m < 4; ++m)
        #pragma unroll
        for (int h = 0; h < 4; ++h) acc[m][h] = (f32x4){0.f, 0.f, 0.f, 0.f};

    auto stage1 = [&](int t) {
        const f16* As = (t < 16) ? Ah : ((t < 32) ? Al : Ah);
        const f16* Bs = (t < 32) ? Bht : Blt;
        const int kofs = (t & 15) * 32;
        f16* dst = lds_f + (t % 5) * 8192 + wv * 512;
        G2L(As + stgA + kofs,           dst);
        G2L(As + stgA + 64 * En + kofs, dst + 2048);
        G2L(Bs + stgB + kofs,           dst + 4096);
        G2L(Bs + stgB + 16 * En + kofs, dst + 4096 + 2048);
    };

    // prologue: tiles 0..3 staged; wait tile0 (12 of tiles 1-3 outstanding)
    stage1(0);
    stage1(1);
    stage1(2);
    stage1(3);
    VM12;
    __builtin_amdgcn_s_barrier();

    #pragma unroll
    for (int t = 0; t < 48; ++t) {
        const f16* Lb = lds_f + (t % 5) * 8192;
        f16x8 af[4], bfr[4];
        #pragma unroll
        for (int m = 0; m < 4; ++m) af[m] = *(const f16x8*)(Lb + aFrag + m * 512);
        #pragma unroll
        for (int h = 0; h < 4; ++h) bfr[h] = *(const f16x8*)(Lb + bFrag + h * 512);
        if (t + 4 < 48) stage1(t + 4);
        __builtin_amdgcn_s_barrier();
        asm volatile("s_waitcnt lgkmcnt(0)" ::: "memory");
        __builtin_amdgcn_sched_barrier(0);
        __builtin_amdgcn_s_setprio(1);
        #pragma unroll
        for (int m = 0; m < 4; ++m) {
            #pragma unroll
            for (int h = 0; h < 4; ++h)
                acc[m][h] = __builtin_amdgcn_mfma_f32_16x16x32_f16(
                    af[m], bfr[h], acc[m][h], 0, 0, 0);
        }
        __builtin_amdgcn_s_setprio(0);
        if (t <= 43)      VM12;  // tile t+1 landed; tiles t+2..t+4 in flight
        else if (t == 44) VM8;   // tiles 46,47 in flight
        else if (t == 45) VM4;   // tile 47 in flight
        else if (t == 46) VM0;   // all landed
        __builtin_amdgcn_s_barrier();
    }

    // epilogue: leaky_relu + head combine + hi/lo split store
    const float w0 = wcomb[0], w1 = wcomb[1], w2 = wcomb[2], w3 = wcomb[3];
    const int q = q0 + wn * 16 + (l & 15);
    const int rbase = m0 + wm * 64 + (l >> 4) * 4;
    #pragma unroll
    for (int m = 0; m < 4; ++m) {
        #pragma unroll
        for (int i = 0; i < 4; ++i) {
            float x0 = acc[m][0][i]; x0 = x0 >= 0.f ? x0 : SLOPE * x0;
            float x1 = acc[m][1][i]; x1 = x1 >= 0.f ? x1 : SLOPE * x1;
            float x2 = acc[m][2][i]; x2 = x2 >= 0.f ? x2 : SLOPE * x2;
            float x3 = acc[m][3][i]; x3 = x3 >= 0.f ? x3 : SLOPE * x3;
            const float c = w0 * x0 + w1 * x1 + w2 * x2 + w3 * x3;
            const f16 ch = (f16)c;
            const f16 cl = (f16)(c - (float)ch);
            const size_t off = (size_t)(rbase + m * 16 + i) * QD + q;
            Ch[off] = ch;
            Cl[off] = cl;
        }
    }
}

// ---------------------------------------------------------------------------
// K2: out[t,b,s] = dot(combined[b,s,:], query[t,b,:]) — RING-5, lead-4.
//   Per batch M=1024(s) N=512(t) K=256x3. 128x128 tile, BK=32,
//   24 K-tiles, 4 waves (2M x 2N), 16 MFMA/phase, vmcnt(12) steady.
// ---------------------------------------------------------------------------
__global__ __launch_bounds__(256) void gemm2_kernel(
    const f16* __restrict__ Ch, const f16* __restrict__ Cl,
    const f16* __restrict__ Qh, const f16* __restrict__ Ql,
    const void* __restrict__ maskp, const float* __restrict__ wcomb,
    const int* __restrict__ flag,
    float* __restrict__ out)
{
    __shared__ f16 lds2[40960];   // 5 slots x (A 4096 + B 4096) f16 = 80 KB

    const int tid = threadIdx.x;
    const int l  = tid & 63;
    const int wv = tid >> 6;
    const int wm = wv >> 1;          // s half
    const int wn = wv & 1;           // t half
    const int b  = blockIdx.z;
    const int s0 = blockIdx.x * 128;
    const int t0 = blockIdx.y * 128;

    const int rowc = tid >> 2;
    const int xk   = ((tid & 3) ^ ((rowc >> 1) & 3)) * 8;
    const int stgA = (b * Sn + s0 + rowc) * QD + xk;   // +64*QD instr2
    const int stgB = (b * Tn + t0 + rowc) * QD + xk;   // +64*QD instr2

    const int xf  = ((l >> 1) & 3);
    const int aFrag = (wm * 64 + (l & 15)) * 32 + (((l >> 4) ^ xf) * 8);
    const int bFrag = 4096 + (wn * 64 + (l & 15)) * 32 + (((l >> 4) ^ xf) * 8);

    f32x4 acc[4][4];
    #pragma unroll
    for (int m = 0; m < 4; ++m)
        #pragma unroll
        for (int n = 0; n < 4; ++n) acc[m][n] = (f32x4){0.f, 0.f, 0.f, 0.f};

    auto stage1 = [&](int t) {
        const f16* As = (t < 8) ? Ch : ((t < 16) ? Cl : Ch);
        const f16* Bs = (t < 16) ? Qh : Ql;
        const int kofs = (t & 7) * 32;
        f16* dst = lds2 + (t % 5) * 8192 + wv * 512;
        G2L(As + stgA + kofs,           dst);
        G2L(As + stgA + 64 * QD + kofs, dst + 2048);
        G2L(Bs + stgB + kofs,           dst + 4096);
        G2L(Bs + stgB + 64 * QD + kofs, dst + 4096 + 2048);
    };

    stage1(0);
    stage1(1);
    stage1(2);
    stage1(3);
    VM12;
    __builtin_amdgcn_s_barrier();

    #pragma unroll
    for (int kt = 0; kt < 24; ++kt) {
        const f16* Lb = lds2 + (kt % 5) * 8192;
        f16x8 af[4], bfr[4];
        #pragma unroll
        for (int m = 0; m < 4; ++m) af[m] = *(const f16x8*)(Lb + aFrag + m * 512);
        #pragma unroll
        for (int n = 0; n < 4; ++n) bfr[n] = *(const f16x8*)(Lb + bFrag + n * 512);
        if (kt + 4 < 24) stage1(kt + 4);
        __builtin_amdgcn_s_barrier();
        asm volatile("s_waitcnt lgkmcnt(0)" ::: "memory");
        __builtin_amdgcn_sched_barrier(0);
        __builtin_amdgcn_s_setprio(1);
        #pragma unroll
        for (int m = 0; m < 4; ++m) {
            #pragma unroll
            for (int n = 0; n < 4; ++n)
                acc[m][n] = __builtin_amdgcn_mfma_f32_16x16x32_f16(
                    af[m], bfr[n], acc[m][n], 0, 0, 0);
        }
        __builtin_amdgcn_s_setprio(0);
        if (kt <= 19)      VM12;
        else if (kt == 20) VM8;
        else if (kt == 21) VM4;
        else if (kt == 22) VM0;
        __builtin_amdgcn_s_barrier();
    }

    // epilogue: mask override + coalesced float4 stores along s
    const float sumw = wcomb[0] + wcomb[1] + wcomb[2] + wcomb[3];
    const float maskval = NEG_INF * sumw;
    const bool is_int = (flag[0] != 0);
    const int rbase = s0 + wm * 64 + (l >> 4) * 4;

    bool msk[4][4];
    #pragma unroll
    for (int m = 0; m < 4; ++m)
        #pragma unroll
        for (int i = 0; i < 4; ++i) {
            const int idx = b * Sn + rbase + m * 16 + i;
            int mm;
            if (is_int) mm = ((const int*)maskp)[idx];
            else        mm = (int)((const unsigned char*)maskp)[idx];
            msk[m][i] = (mm != 0);
        }

    #pragma unroll
    for (int m = 0; m < 4; ++m)
        #pragma unroll
        for (int n = 0; n < 4; ++n) {
            const int t = t0 + wn * 64 + n * 16 + (l & 15);
            float vals[4];
            #pragma unroll
            for (int i = 0; i < 4; ++i)
                vals[i] = msk[m][i] ? maskval : acc[m][n][i];
            *(float4*)(out + ((size_t)t * Bn + b) * Sn + rbase + m * 16)
                = make_float4(vals[0], vals[1], vals[2], vals[3]);
        }
}

// ---------------------------------------------------------------------------
// K3: in-place softmax over last dim (S=1024). One block per (t,b) row.
// ---------------------------------------------------------------------------
__global__ __launch_bounds__(256) void softmax_kernel(float* __restrict__ out) {
    const size_t row = blockIdx.x;
    float* p = out + row * (size_t)Sn;
    const int tid = threadIdx.x;
    const int lane = tid & 63, wave = tid >> 6;

    float4 v = ((const float4*)p)[tid];

    float m = fmaxf(fmaxf(v.x, v.y), fmaxf(v.z, v.w));
    #pragma unroll
    for (int off = 32; off; off >>= 1) m = fmaxf(m, __shfl_down(m, off));
    __shared__ float smax[4];
    __shared__ float sm_all;
    if (lane == 0) smax[wave] = m;
    __syncthreads();
    if (tid == 0) sm_all = fmaxf(fmaxf(smax[0], smax[1]), fmaxf(smax[2], smax[3]));
    __syncthreads();
    m = sm_all;

    float e0 = __expf(v.x - m), e1 = __expf(v.y - m);
    float e2 = __expf(v.z - m), e3 = __expf(v.w - m);
    float s = e0 + e1 + e2 + e3;
    #pragma unroll
    for (int off = 32; off; off >>= 1) s += __shfl_down(s, off);
    __shared__ float ssum[4];
    __shared__ float ss_all;
    if (lane == 0) ssum[wave] = s;
    __syncthreads();
    if (tid == 0) ss_all = ssum[0] + ssum[1] + ssum[2] + ssum[3];
    __syncthreads();
    const float inv = 1.0f / ss_all;

    ((float4*)p)[tid] = make_float4(e0 * inv, e1 * inv, e2 * inv, e3 * inv);
}

// ---------------------------------------------------------------------------
extern "C" void kernel_launch(void* const* d_in, const int* in_sizes, int n_in,
                              void* d_out, int out_size, void* d_ws, size_t ws_size,
                              hipStream_t stream) {
    const float* src   = (const float*)d_in[0];  // (16,1024,512)
    const void*  maskp = d_in[1];                // (16,1024) bool/int32
    const float* query = (const float*)d_in[2];  // (512,16,256)
    const float* Wsrc  = (const float*)d_in[3];  // (512,1024)
    const float* wcomb = (const float*)d_in[4];  // (4,)
    float* out = (float*)d_out;                  // (512,16,1024)

    // workspace layout (total 50 MB + 256 B; Qh/Ql alias Ah/Al after gemm1)
    constexpr size_t MB = 1024 * 1024;
    char* ws = (char*)d_ws;
    int* flag = (int*)ws;
    f16* Ah  = (f16*)(ws + 256);
    f16* Al  = (f16*)(ws + 256 + 16 * MB);
    f16* Bht = (f16*)(ws + 256 + 32 * MB);
    f16* Blt = (f16*)(ws + 256 + 33 * MB);
    f16* Ch  = (f16*)(ws + 256 + 34 * MB);
    f16* Cl  = (f16*)(ws + 256 + 42 * MB);
    f16* Qh  = (f16*)(ws + 256);            // aliases Ah (free after gemm1)
    f16* Ql  = (f16*)(ws + 256 + 4 * MB);   // aliases Ah region

    detect_mask_kernel<<<1, 256, 0, stream>>>((const unsigned char*)maskp, flag);

    conv_a_kernel<<<(Mn * En) / (256 * 4), 256, 0, stream>>>(src, Ah, Al);
    {
        dim3 grid((Hn * QD) / 64, En / 64);  // (16, 8)
        conv_b_kernel<<<grid, 256, 0, stream>>>(Wsrc, Bht, Blt);
    }
    {
        dim3 grid(Mn / 128, QD / 32);        // (128, 8) = 1024 blocks, 2/CU
        gemm1_kernel<<<grid, 256, 0, stream>>>(Ah, Al, Bht, Blt, wcomb, Ch, Cl);
    }
    conv_q_kernel<<<(Tn * Bn) / 4, 256, 0, stream>>>(query, Qh, Ql);
    {
        dim3 grid(Sn / 128, Tn / 128, Bn);   // (8, 4, 16) = 512 blocks, 2/CU
        gemm2_kernel<<<grid, 256, 0, stream>>>(Ch, Cl, Qh, Ql, maskp, wcomb, flag, out);
    }
    softmax_kernel<<<Tn * Bn, 256, 0, stream>>>(out);
}

// Round 10
// 121.141 us; speedup vs baseline: 1.0517x; 1.0517x over previous
//
#include <hip/hip_runtime.h>
#include <hip/hip_bf16.h>
#include <cstdint>

// Problem dims (fixed by reference setup_inputs)
constexpr int Bn = 16;    // batch
constexpr int Sn = 1024;  // source length
constexpr int Tn = 512;   // query steps
constexpr int QD = 256;   // query vec size
constexpr int En = 512;   // src encoding size
constexpr int Hn = 4;     // heads
constexpr float SLOPE = 0.01f;   // jax.nn.leaky_relu default
constexpr float NEG_INF = -1e9f;
constexpr int Mn = Bn * Sn;      // 16384 rows of the projection GEMM

typedef _Float16 f16;
typedef f16 f16x4 __attribute__((ext_vector_type(4)));
typedef f16 f16x8 __attribute__((ext_vector_type(8)));
typedef float f32x4 __attribute__((ext_vector_type(4)));

// async global->LDS, 16B per lane; dest = wave-uniform base + lane*16
#define G2L(g, l) __builtin_amdgcn_global_load_lds(                      \
    (const __attribute__((address_space(1))) void*)(g),                  \
    (__attribute__((address_space(3))) void*)(l), 16, 0, 0)

#define VM6 asm volatile("s_waitcnt vmcnt(6)" ::: "memory")
#define VM4 asm volatile("s_waitcnt vmcnt(4)" ::: "memory")
#define VM0 asm volatile("s_waitcnt vmcnt(0)" ::: "memory")
#define LG0 asm volatile("s_waitcnt lgkmcnt(0)" ::: "memory")

// ---------------------------------------------------------------------------
// K0: detect mask dtype (bool bytes vs int32) — writes flag (1 = int32) to ws
// ---------------------------------------------------------------------------
__global__ void detect_mask_kernel(const unsigned char* __restrict__ mask_bytes,
                                   int* __restrict__ flag) {
    __shared__ int cnt;
    if (threadIdx.x == 0) cnt = 0;
    __syncthreads();
    int local = 0;
    for (int p = threadIdx.x; p < 4096; p += 256) {
        if ((p & 3) != 0 && mask_bytes[p] != 0) local++;
    }
    atomicAdd(&cnt, local);
    __syncthreads();
    if (threadIdx.x == 0) flag[0] = (cnt == 0) ? 1 : 0;
}

// ---------------------------------------------------------------------------
// C1: split src (16384x512 f32) into Ah + Al (f16 row-major), exact hi/lo
// ---------------------------------------------------------------------------
__global__ __launch_bounds__(256) void conv_a_kernel(
    const float* __restrict__ src, f16* __restrict__ Ah, f16* __restrict__ Al)
{
    const size_t i4 = (size_t)blockIdx.x * 256 + threadIdx.x;
    const size_t base = i4 * 4;
    const float4 v = *(const float4*)(src + base);
    f16x4 hi, lo;
    const float xs[4] = {v.x, v.y, v.z, v.w};
    #pragma unroll
    for (int j = 0; j < 4; ++j) {
        f16 h = (f16)xs[j];
        hi[j] = h;
        lo[j] = (f16)(xs[j] - (float)h);
    }
    *(f16x4*)(Ah + base) = hi;
    *(f16x4*)(Al + base) = lo;
}

// ---------------------------------------------------------------------------
// C2: W (512x1024 f32) -> Bht, Blt (1024x512 f16) transposed + hi/lo split
// ---------------------------------------------------------------------------
__global__ __launch_bounds__(256) void conv_b_kernel(
    const float* __restrict__ W, f16* __restrict__ Bht, f16* __restrict__ Blt)
{
    __shared__ float T[64][65];
    const int tid = threadIdx.x;
    const int n0 = blockIdx.x * 64;
    const int k0 = blockIdx.y * 64;
    #pragma unroll
    for (int p = 0; p < 4; ++p) {
        const int e = p * 256 + tid;
        const int r = e >> 4;
        const int c4 = e & 15;
        const float4 v = *(const float4*)(W + (size_t)(k0 + r) * (Hn * QD) + n0 + c4 * 4);
        T[r][c4 * 4 + 0] = v.x; T[r][c4 * 4 + 1] = v.y;
        T[r][c4 * 4 + 2] = v.z; T[r][c4 * 4 + 3] = v.w;
    }
    __syncthreads();
    #pragma unroll
    for (int p = 0; p < 4; ++p) {
        const int e = p * 256 + tid;
        const int r = e >> 4;
        const int c4 = e & 15;
        f16x4 hi, lo;
        #pragma unroll
        for (int j = 0; j < 4; ++j) {
            const float x = T[c4 * 4 + j][r];
            f16 h = (f16)x;
            hi[j] = h;
            lo[j] = (f16)(x - (float)h);
        }
        const size_t off = (size_t)(n0 + r) * En + k0 + c4 * 4;
        *(f16x4*)(Bht + off) = hi;
        *(f16x4*)(Blt + off) = lo;
    }
}

// ---------------------------------------------------------------------------
// C3: split query (512,16,256) f32 -> Qh, Ql (b,t,q) f16.
// ---------------------------------------------------------------------------
__global__ __launch_bounds__(256) void conv_q_kernel(
    const float* __restrict__ query, f16* __restrict__ Qh, f16* __restrict__ Ql)
{
    const int tid = threadIdx.x;
    const int rloc = tid >> 6;
    const int lane = tid & 63;
    const int row = blockIdx.x * 4 + rloc;   // (t,b) pair, t-major
    const int t = row >> 4, b = row & 15;
    const float4 v = *(const float4*)(query + (size_t)row * QD + lane * 4);
    f16x4 hi, lo;
    const float xs[4] = {v.x, v.y, v.z, v.w};
    #pragma unroll
    for (int j = 0; j < 4; ++j) {
        f16 h = (f16)xs[j];
        hi[j] = h;
        lo[j] = (f16)(xs[j] - (float)h);
    }
    const size_t off = ((size_t)(b * Tn + t)) * QD + lane * 4;
    *(f16x4*)(Qh + off) = hi;
    *(f16x4*)(Ql + off) = lo;
}

// ---------------------------------------------------------------------------
// K1: 128(rows) x 256(cols = 64q x 4heads) tile, BK=32, ring-3, lead-2.
//   48 K-tiles (3 split-phases x 16). 4 waves (2M x 2N), per-wave 64x128
//   (4 m-frags x 8 col-frags) = 32 MFMA/phase. LDS 72 KB -> 2 blk/CU.
//   R10: NO forced lgkm-drain before MFMA (backend emits fine-grained
//   lgkmcnt; MFMAs interleave with ds_reads), ONE barrier per phase.
//   End-of-phase: counted vmcnt (tile t+1 landed) + trivially-satisfied
//   lgkmcnt(0) (WAR on slot (t+2)%3 airtight) + s_barrier.
//   XOR-chunk scheme (validated R6-R9): slot k4 = global k4 ^ ((row>>1)&3).
// ---------------------------------------------------------------------------
__global__ __launch_bounds__(256) void gemm1_kernel(
    const f16* __restrict__ Ah, const f16* __restrict__ Al,
    const f16* __restrict__ Bht, const f16* __restrict__ Blt,
    const float* __restrict__ wcomb,
    f16* __restrict__ Ch, f16* __restrict__ Cl)
{
    __shared__ f16 lds_f[36864];   // 3 slots x 12288 f16 = 72 KB

    const int tid = threadIdx.x;
    const int l  = tid & 63;
    const int wv = tid >> 6;         // 0..3
    const int wm = wv >> 1;          // M half (64 rows)
    const int wn = wv & 1;           // q half (32 q)
    const int m0 = blockIdx.x * 128;
    const int q0 = blockIdx.y * 64;

    // staging constants: chunk c = i*256 + tid; row/col = c>>2, k4 = c&3
    const int rc  = tid >> 2;                                   // 0..63
    const int xk  = ((tid & 3) ^ ((tid >> 3) & 3)) * 8;         // XOR'd k-chunk
    const int stgA = (m0 + rc) * En + xk;        // A rows rc, rc+64
    const int stgB = (q0 + rc) * En + xk;        // B strips: +i*QD*En per head

    // fragment ds_read bases (f16 idx); xor nibble lane-constant
    const int xf  = (l >> 1) & 3;
    const int kx  = ((l >> 4) ^ xf) * 8;
    const int aFrag = (wm * 64 + (l & 15)) * 32 + kx;            // + m*512
    const int bFrag = 4096 + (wn * 32 + (l & 15)) * 32 + kx;     // + h*2048 + qs*512

    f32x4 acc[4][8];   // [m][f = h*2 + qsub]
    #pragma unroll
    for (int m = 0; m < 4; ++m)
        #pragma unroll
        for (int f = 0; f < 8; ++f) acc[m][f] = (f32x4){0.f, 0.f, 0.f, 0.f};

    auto stage1 = [&](int t) {
        const f16* As = (t < 16) ? Ah : ((t < 32) ? Al : Ah);
        const f16* Bs = (t < 32) ? Bht : Blt;
        const int kofs = (t & 15) * 32;
        f16* dst = lds_f + (t % 3) * 12288 + wv * 512;
        G2L(As + stgA + kofs,                dst);
        G2L(As + stgA + 64 * En + kofs,      dst + 2048);
        G2L(Bs + stgB + kofs,                dst + 4096);
        G2L(Bs + stgB + QD * En + kofs,      dst + 4096 + 2048);
        G2L(Bs + stgB + 2 * QD * En + kofs,  dst + 4096 + 4096);
        G2L(Bs + stgB + 3 * QD * En + kofs,  dst + 4096 + 6144);
    };

    // prologue: tiles 0,1 staged; wait tile0 (6 of tile1 outstanding)
    stage1(0);
    stage1(1);
    VM6;
    __builtin_amdgcn_s_barrier();

    #pragma unroll
    for (int t = 0; t < 48; ++t) {
        if (t + 2 < 48) stage1(t + 2);   // issue next-next tile first
        const f16* Lb = lds_f + (t % 3) * 12288;
        f16x8 af[4], bfr[8];
        #pragma unroll
        for (int m = 0; m < 4; ++m) af[m] = *(const f16x8*)(Lb + aFrag + m * 512);
        #pragma unroll
        for (int f = 0; f < 8; ++f)
            bfr[f] = *(const f16x8*)(Lb + bFrag + (f >> 1) * 2048 + (f & 1) * 512);
        __builtin_amdgcn_s_setprio(1);
        #pragma unroll
        for (int m = 0; m < 4; ++m) {
            #pragma unroll
            for (int f = 0; f < 8; ++f)
                acc[m][f] = __builtin_amdgcn_mfma_f32_16x16x32_f16(
                    af[m], bfr[f], acc[m][f], 0, 0, 0);
        }
        __builtin_amdgcn_s_setprio(0);
        if (t <= 45)      VM6;   // tile t+1 landed (tile t+2's 6 remain)
        else if (t == 46) VM0;   // drain: tile 47 landed
        LG0;                      // trivially satisfied; pins WAR for slot reuse
        __builtin_amdgcn_s_barrier();
    }

    // epilogue: leaky_relu + head combine + hi/lo split store
    const float w0 = wcomb[0], w1 = wcomb[1], w2 = wcomb[2], w3 = wcomb[3];
    const int rbase = m0 + wm * 64 + (l >> 4) * 4;
    #pragma unroll
    for (int m = 0; m < 4; ++m) {
        #pragma unroll
        for (int qs = 0; qs < 2; ++qs) {
            const int q = q0 + wn * 32 + qs * 16 + (l & 15);
            #pragma unroll
            for (int i = 0; i < 4; ++i) {
                float x0 = acc[m][0 + qs][i]; x0 = x0 >= 0.f ? x0 : SLOPE * x0;
                float x1 = acc[m][2 + qs][i]; x1 = x1 >= 0.f ? x1 : SLOPE * x1;
                float x2 = acc[m][4 + qs][i]; x2 = x2 >= 0.f ? x2 : SLOPE * x2;
                float x3 = acc[m][6 + qs][i]; x3 = x3 >= 0.f ? x3 : SLOPE * x3;
                const float c = w0 * x0 + w1 * x1 + w2 * x2 + w3 * x3;
                const f16 ch = (f16)c;
                const f16 cl = (f16)(c - (float)ch);
                const size_t off = (size_t)(rbase + m * 16 + i) * QD + q;
                Ch[off] = ch;
                Cl[off] = cl;
            }
        }
    }
}

// ---------------------------------------------------------------------------
// K2: out[t,b,s] = dot(combined[b,s,:], query[t,b,:]) — ring-3, lead-2,
//   same de-serialized phase structure as K1. Per batch M=1024 N=512 K=256x3.
//   128x128 tile, BK=32, 24 K-tiles, 4 waves (2M x 2N), 16 MFMA/phase.
// ---------------------------------------------------------------------------
__global__ __launch_bounds__(256) void gemm2_kernel(
    const f16* __restrict__ Ch, const f16* __restrict__ Cl,
    const f16* __restrict__ Qh, const f16* __restrict__ Ql,
    const void* __restrict__ maskp, const float* __restrict__ wcomb,
    const int* __restrict__ flag,
    float* __restrict__ out)
{
    __shared__ f16 lds2[24576];   // 3 slots x (A 4096 + B 4096) f16

    const int tid = threadIdx.x;
    const int l  = tid & 63;
    const int wv = tid >> 6;
    const int wm = wv >> 1;          // s half
    const int wn = wv & 1;           // t half
    const int b  = blockIdx.z;
    const int s0 = blockIdx.x * 128;
    const int t0 = blockIdx.y * 128;

    const int rowc = tid >> 2;
    const int xk   = ((tid & 3) ^ ((rowc >> 1) & 3)) * 8;
    const int stgA = (b * Sn + s0 + rowc) * QD + xk;   // +64*QD instr2
    const int stgB = (b * Tn + t0 + rowc) * QD + xk;   // +64*QD instr2

    const int xf  = ((l >> 1) & 3);
    const int aFrag = (wm * 64 + (l & 15)) * 32 + (((l >> 4) ^ xf) * 8);
    const int bFrag = 4096 + (wn * 64 + (l & 15)) * 32 + (((l >> 4) ^ xf) * 8);

    f32x4 acc[4][4];
    #pragma unroll
    for (int m = 0; m < 4; ++m)
        #pragma unroll
        for (int n = 0; n < 4; ++n) acc[m][n] = (f32x4){0.f, 0.f, 0.f, 0.f};

    auto stage1 = [&](int t) {
        const f16* As = (t < 8) ? Ch : ((t < 16) ? Cl : Ch);
        const f16* Bs = (t < 16) ? Qh : Ql;
        const int kofs = (t & 7) * 32;
        f16* dst = lds2 + (t % 3) * 8192 + wv * 512;
        G2L(As + stgA + kofs,           dst);
        G2L(As + stgA + 64 * QD + kofs, dst + 2048);
        G2L(Bs + stgB + kofs,           dst + 4096);
        G2L(Bs + stgB + 64 * QD + kofs, dst + 4096 + 2048);
    };

    stage1(0);
    stage1(1);
    VM4;
    __builtin_amdgcn_s_barrier();

    #pragma unroll
    for (int kt = 0; kt < 24; ++kt) {
        if (kt + 2 < 24) stage1(kt + 2);
        const f16* Lb = lds2 + (kt % 3) * 8192;
        f16x8 af[4], bfr[4];
        #pragma unroll
        for (int m = 0; m < 4; ++m) af[m] = *(const f16x8*)(Lb + aFrag + m * 512);
        #pragma unroll
        for (int n = 0; n < 4; ++n) bfr[n] = *(const f16x8*)(Lb + bFrag + n * 512);
        __builtin_amdgcn_s_setprio(1);
        #pragma unroll
        for (int m = 0; m < 4; ++m) {
            #pragma unroll
            for (int n = 0; n < 4; ++n)
                acc[m][n] = __builtin_amdgcn_mfma_f32_16x16x32_f16(
                    af[m], bfr[n], acc[m][n], 0, 0, 0);
        }
        __builtin_amdgcn_s_setprio(0);
        if (kt <= 21)      VM4;
        else if (kt == 22) VM0;
        LG0;
        __builtin_amdgcn_s_barrier();
    }

    // epilogue: mask override + coalesced float4 stores along s
    const float sumw = wcomb[0] + wcomb[1] + wcomb[2] + wcomb[3];
    const float maskval = NEG_INF * sumw;
    const bool is_int = (flag[0] != 0);
    const int rbase = s0 + wm * 64 + (l >> 4) * 4;

    bool msk[4][4];
    #pragma unroll
    for (int m = 0; m < 4; ++m)
        #pragma unroll
        for (int i = 0; i < 4; ++i) {
            const int idx = b * Sn + rbase + m * 16 + i;
            int mm;
            if (is_int) mm = ((const int*)maskp)[idx];
            else        mm = (int)((const unsigned char*)maskp)[idx];
            msk[m][i] = (mm != 0);
        }

    #pragma unroll
    for (int m = 0; m < 4; ++m)
        #pragma unroll
        for (int n = 0; n < 4; ++n) {
            const int t = t0 + wn * 64 + n * 16 + (l & 15);
            float vals[4];
            #pragma unroll
            for (int i = 0; i < 4; ++i)
                vals[i] = msk[m][i] ? maskval : acc[m][n][i];
            *(float4*)(out + ((size_t)t * Bn + b) * Sn + rbase + m * 16)
                = make_float4(vals[0], vals[1], vals[2], vals[3]);
        }
}

// ---------------------------------------------------------------------------
// K3: in-place softmax over last dim (S=1024). One block per (t,b) row.
// ---------------------------------------------------------------------------
__global__ __launch_bounds__(256) void softmax_kernel(float* __restrict__ out) {
    const size_t row = blockIdx.x;
    float* p = out + row * (size_t)Sn;
    const int tid = threadIdx.x;
    const int lane = tid & 63, wave = tid >> 6;

    float4 v = ((const float4*)p)[tid];

    float m = fmaxf(fmaxf(v.x, v.y), fmaxf(v.z, v.w));
    #pragma unroll
    for (int off = 32; off; off >>= 1) m = fmaxf(m, __shfl_down(m, off));
    __shared__ float smax[4];
    __shared__ float sm_all;
    if (lane == 0) smax[wave] = m;
    __syncthreads();
    if (tid == 0) sm_all = fmaxf(fmaxf(smax[0], smax[1]), fmaxf(smax[2], smax[3]));
    __syncthreads();
    m = sm_all;

    float e0 = __expf(v.x - m), e1 = __expf(v.y - m);
    float e2 = __expf(v.z - m), e3 = __expf(v.w - m);
    float s = e0 + e1 + e2 + e3;
    #pragma unroll
    for (int off = 32; off; off >>= 1) s += __shfl_down(s, off);
    __shared__ float ssum[4];
    __shared__ float ss_all;
    if (lane == 0) ssum[wave] = s;
    __syncthreads();
    if (tid == 0) ss_all = ssum[0] + ssum[1] + ssum[2] + ssum[3];
    __syncthreads();
    const float inv = 1.0f / ss_all;

    ((float4*)p)[tid] = make_float4(e0 * inv, e1 * inv, e2 * inv, e3 * inv);
}

// ---------------------------------------------------------------------------
extern "C" void kernel_launch(void* const* d_in, const int* in_sizes, int n_in,
                              void* d_out, int out_size, void* d_ws, size_t ws_size,
                              hipStream_t stream) {
    const float* src   = (const float*)d_in[0];  // (16,1024,512)
    const void*  maskp = d_in[1];                // (16,1024) bool/int32
    const float* query = (const float*)d_in[2];  // (512,16,256)
    const float* Wsrc  = (const float*)d_in[3];  // (512,1024)
    const float* wcomb = (const float*)d_in[4];  // (4,)
    float* out = (float*)d_out;                  // (512,16,1024)

    // workspace layout (total 50 MB + 256 B; Qh/Ql alias Ah/Al after gemm1)
    constexpr size_t MB = 1024 * 1024;
    char* ws = (char*)d_ws;
    int* flag = (int*)ws;
    f16* Ah  = (f16*)(ws + 256);
    f16* Al  = (f16*)(ws + 256 + 16 * MB);
    f16* Bht = (f16*)(ws + 256 + 32 * MB);
    f16* Blt = (f16*)(ws + 256 + 33 * MB);
    f16* Ch  = (f16*)(ws + 256 + 34 * MB);
    f16* Cl  = (f16*)(ws + 256 + 42 * MB);
    f16* Qh  = (f16*)(ws + 256);            // aliases Ah (free after gemm1)
    f16* Ql  = (f16*)(ws + 256 + 4 * MB);   // aliases Ah region

    detect_mask_kernel<<<1, 256, 0, stream>>>((const unsigned char*)maskp, flag);

    conv_a_kernel<<<(Mn * En) / (256 * 4), 256, 0, stream>>>(src, Ah, Al);
    {
        dim3 grid((Hn * QD) / 64, En / 64);  // (16, 8)
        conv_b_kernel<<<grid, 256, 0, stream>>>(Wsrc, Bht, Blt);
    }
    {
        dim3 grid(Mn / 128, QD / 64);        // (128, 4) = 512 blocks, 2/CU
        gemm1_kernel<<<grid, 256, 0, stream>>>(Ah, Al, Bht, Blt, wcomb, Ch, Cl);
    }
    conv_q_kernel<<<(Tn * Bn) / 4, 256, 0, stream>>>(query, Qh, Ql);
    {
        dim3 grid(Sn / 128, Tn / 128, Bn);   // (8, 4, 16) = 512 blocks
        gemm2_kernel<<<grid, 256, 0, stream>>>(Ch, Cl, Qh, Ql, maskp, wcomb, flag, out);
    }
    softmax_kernel<<<Tn * Bn, 256, 0, stream>>>(out);
}